// Round 1
// baseline (258.667 us; speedup 1.0000x reference)
//
#include <hip/hip_runtime.h>

// NCC forces, 192^3 fp32, 5x5x5 box sums + gradients, fully fused.
// Block = 16x16 (x,y) tile marching over a 24-slice z segment.
// LDS: 4-deep ring of 20x20 raw slices (m,f) + transient x-sum buffer.
// Per-thread: 5-deep register shift-ring of 2D box sums (5 fields).

#define DD 192
#define HH 192
#define WW 192
#define NVOX (DD * HH * WW)
#define TS 16          // tile size in x and y
#define RT (TS + 4)    // raw tile with +/-2 halo = 20
#define ZSEG 24        // z slices per block

__global__ __launch_bounds__(256)
void ncc_forces_kernel(const float* __restrict__ mimg,
                       const float* __restrict__ fimg,
                       const int*   __restrict__ mmask,
                       const int*   __restrict__ fmask,
                       float* __restrict__ out)
{
    __shared__ float rawm[4][RT][RT];   // raw slice ring (z gradient needs z-1..z+1; box loads z+2)
    __shared__ float rawf[4][RT][RT];
    __shared__ float xs[5][RT][TS];     // x-summed 5 fields for current slice

    const int tx = threadIdx.x;         // 0..15
    const int ty = threadIdx.y;         // 0..15
    const int tid = ty * TS + tx;
    const int x0 = blockIdx.x * TS;
    const int y0 = blockIdx.y * TS;
    const int z0 = blockIdx.z * ZSEG;
    const int z1 = z0 + ZSEG;

    // 5-deep shift ring of per-thread 2D box sums: ring[0]=oldest .. ring[4]=newest
    float ring[5][5];
#pragma unroll
    for (int s = 0; s < 5; ++s)
#pragma unroll
        for (int f = 0; f < 5; ++f) ring[s][f] = 0.f;

    for (int zc = z0 - 2; zc <= z1 + 1; ++zc) {
        const int s4 = (zc + 4) & 3;    // raw ring slot for slice zc (zc >= -2)
        const bool zin = (zc >= 0) && (zc < DD);

        // ---- 1. stage raw slice zc (zero-padded = conv SAME semantics) ----
        for (int i = tid; i < RT * RT; i += 256) {
            const int iy = i / RT;
            const int ix = i - iy * RT;
            const int gx = x0 - 2 + ix;
            const int gy = y0 - 2 + iy;
            float vm = 0.f, vf = 0.f;
            if (zin && gx >= 0 && gx < WW && gy >= 0 && gy < HH) {
                const int gidx = (zc * HH + gy) * WW + gx;
                vm = mimg[gidx];
                vf = fimg[gidx];
            }
            rawm[s4][iy][ix] = vm;
            rawf[s4][iy][ix] = vf;
        }
        __syncthreads();

        // ---- 2. x-sums (5-wide) of the 5 product fields ----
        for (int i = tid; i < RT * TS; i += 256) {   // 320 tasks
            const int y  = i >> 4;
            const int xo = i & 15;
            float sm = 0.f, sf = 0.f, smm = 0.f, sff = 0.f, smf = 0.f;
#pragma unroll
            for (int dx = 0; dx < 5; ++dx) {
                const float a = rawm[s4][y][xo + dx];
                const float b = rawf[s4][y][xo + dx];
                sm += a; sf += b; smm += a * a; sff += b * b; smf += a * b;
            }
            xs[0][y][xo] = sm;
            xs[1][y][xo] = sf;
            xs[2][y][xo] = smm;
            xs[3][y][xo] = sff;
            xs[4][y][xo] = smf;
        }
        __syncthreads();

        // ---- 3. y-sums (5-wide) -> push into register shift-ring ----
        float s2d[5];
#pragma unroll
        for (int f = 0; f < 5; ++f) {
            float s = 0.f;
#pragma unroll
            for (int dy = 0; dy < 5; ++dy) s += xs[f][ty + dy][tx];
            s2d[f] = s;
        }
#pragma unroll
        for (int s = 0; s < 4; ++s)
#pragma unroll
            for (int f = 0; f < 5; ++f) ring[s][f] = ring[s + 1][f];
#pragma unroll
        for (int f = 0; f < 5; ++f) ring[4][f] = s2d[f];

        // ---- 4. emit output for z = zc - 2 (window z-2..z+2 == ring[0..4]) ----
        const int z = zc - 2;
        if (z >= z0 && z < z1) {
            float sum_m = 0.f, sum_f = 0.f, sum_mm = 0.f, sum_ff = 0.f, sum_mf = 0.f;
#pragma unroll
            for (int s = 0; s < 5; ++s) {
                sum_m  += ring[s][0];
                sum_f  += ring[s][1];
                sum_mm += ring[s][2];
                sum_ff += ring[s][3];
                sum_mf += ring[s][4];
            }
            const int gx = x0 + tx, gy = y0 + ty;
            const int sz  = (z + 4) & 3;   // slot of slice z
            const int szm = (z + 3) & 3;   // z-1
            const int szp = (z + 5) & 3;   // z+1
            const int cy = ty + 2, cx = tx + 2;
            const float mc = rawm[sz][cy][cx];
            const float fc = rawf[sz][cy][cx];

            // gradients: central interior, one-sided edges (jnp.gradient semantics)
            float gxm, gxf, gym, gyf, gzm, gzf;
            if (gx == 0)          { gxm = rawm[sz][cy][cx + 1] - mc;  gxf = rawf[sz][cy][cx + 1] - fc; }
            else if (gx == WW-1)  { gxm = mc - rawm[sz][cy][cx - 1];  gxf = fc - rawf[sz][cy][cx - 1]; }
            else {
                gxm = 0.5f * (rawm[sz][cy][cx + 1] - rawm[sz][cy][cx - 1]);
                gxf = 0.5f * (rawf[sz][cy][cx + 1] - rawf[sz][cy][cx - 1]);
            }
            if (gy == 0)          { gym = rawm[sz][cy + 1][cx] - mc;  gyf = rawf[sz][cy + 1][cx] - fc; }
            else if (gy == HH-1)  { gym = mc - rawm[sz][cy - 1][cx];  gyf = fc - rawf[sz][cy - 1][cx]; }
            else {
                gym = 0.5f * (rawm[sz][cy + 1][cx] - rawm[sz][cy - 1][cx]);
                gyf = 0.5f * (rawf[sz][cy + 1][cx] - rawf[sz][cy - 1][cx]);
            }
            if (z == 0)           { gzm = rawm[szp][cy][cx] - mc;     gzf = rawf[szp][cy][cx] - fc; }
            else if (z == DD-1)   { gzm = mc - rawm[szm][cy][cx];     gzf = fc - rawf[szm][cy][cx]; }
            else {
                gzm = 0.5f * (rawm[szp][cy][cx] - rawm[szm][cy][cx]);
                gzf = 0.5f * (rawf[szp][cy][cx] - rawf[szm][cy][cx]);
            }

            const int vidx = (z * HH + gy) * WW + gx;
            const float u = ((mmask[vidx] != 0) || (fmask[vidx] != 0)) ? 1.0f : 0.0f;

            // epilogue: exact reference algebra
            const float npix = 125.0f;
            const float mean_m = sum_m / npix;
            const float mean_f = sum_f / npix;
            const float var_m = sum_mm - 2.0f * mean_m * sum_m + npix * mean_m * mean_m;
            const float var_f = sum_ff - 2.0f * mean_f * sum_f + npix * mean_f * mean_f;
            const float var_mf = var_m * var_f;
            const float cross = sum_mf - mean_f * sum_m - mean_m * sum_f + npix * mean_m * mean_f;
            const float mmc = mc - mean_m;
            const float fmc = fc - mean_f;
            const bool ok = (var_mf > 1e-5f) && (var_f > 1e-5f) && (fmc != 0.0f) && (mmc != 0.0f);
            float factor = 0.0f;
            if (ok) factor = 2.0f * cross / var_mf * (mmc - cross * fmc / var_f);

            const float nf = -factor * 0.5f * u;
            out[vidx]            = nf * (gzm + gzf);   // channel 0: d/dD
            out[NVOX + vidx]     = nf * (gym + gyf);   // channel 1: d/dH
            out[2 * NVOX + vidx] = nf * (gxm + gxf);   // channel 2: d/dW
        }
        __syncthreads();   // protect raw ring slices read above from next load
    }
}

extern "C" void kernel_launch(void* const* d_in, const int* in_sizes, int n_in,
                              void* d_out, int out_size, void* d_ws, size_t ws_size,
                              hipStream_t stream)
{
    const float* mimg  = (const float*)d_in[0];
    const float* fimg  = (const float*)d_in[1];
    const int*   mmask = (const int*)d_in[2];
    const int*   fmask = (const int*)d_in[3];
    float* out = (float*)d_out;

    dim3 grid(WW / TS, HH / TS, DD / ZSEG);   // 12 x 12 x 8 = 1152 blocks
    dim3 block(TS, TS, 1);                    // 256 threads
    hipLaunchKernelGGL(ncc_forces_kernel, grid, block, 0, stream,
                       mimg, fimg, mmask, fmask, out);
}

// Round 2
// 230.005 us; speedup vs baseline: 1.1246x; 1.1246x over previous
//
#include <hip/hip_runtime.h>

// NCC forces, 192^3 fp32 — fused box-sum + gradient + epilogue.
// Round 2: latency-focused restructure.
//  - ZSEG 24->12 : 2304 blocks (more TLP)
//  - raw ring 4->5 deep : write slot disjoint from read slots -> 2 barriers/slice
//  - staging rows widened to 24 (aligned) : pure float4 global loads, one per
//    thread, software-pipelined one full z-iteration ahead (regs -> LDS)
//  - mask words prefetched at iteration top, consumed at emit

#define DD 192
#define HH 192
#define WW 192
#define NVOX (DD * HH * WW)
#define TS 16          // output tile 16x16
#define RR 20          // staged rows   = TS + 4
#define RW 24          // staged row width (x0-4 .. x0+20, float4-aligned)
#define ZSEG 12
#define NRING 5

__global__ __launch_bounds__(256)
void ncc_forces_kernel(const float* __restrict__ mimg,
                       const float* __restrict__ fimg,
                       const int*   __restrict__ mmask,
                       const int*   __restrict__ fmask,
                       float* __restrict__ out)
{
    __shared__ float rawm[NRING][RR][RW];   // 9600 B
    __shared__ float rawf[NRING][RR][RW];   // 9600 B
    __shared__ float xs[5][RR][TS];         // 6400 B   (25.6 KB total)

    const int tx = threadIdx.x;             // 0..15
    const int ty = threadIdx.y;             // 0..15
    const int tid = ty * TS + tx;
    const int x0 = blockIdx.x * TS;
    const int y0 = blockIdx.y * TS;
    const int z0 = blockIdx.z * ZSEG;
    const int z1 = z0 + ZSEG;

    // ---- persistent staging task: 240 tasks = 2 images x 20 rows x 6 quads ----
    const int  simg   = tid / 120;              // 0 = moving, 1 = fixed, 2 = idle
    const bool stager = (simg < 2);
    const int  st     = tid - simg * 120;       // 0..119
    const int  srow   = st / 6;                 // 0..19
    const int  squad  = st - srow * 6;          // 0..5
    const int  sgy    = y0 - 2 + srow;
    const int  sgxb   = x0 - 4 + squad * 4;
    const bool rowin  = (sgy >= 0) && (sgy < HH);
    const bool fullx  = (sgxb >= 0) && (sgxb + 3 < WW);
    const float* simg_ptr = (simg == 1) ? fimg : mimg;
    float* slds_base = (simg == 1) ? &rawf[0][0][0] : &rawm[0][0][0];
    const int  sloff = srow * RW + squad * 4;   // offset within a ring slice

    auto prefetch = [&](int zc_, float4& p) {
        p.x = p.y = p.z = p.w = 0.f;
        if (stager && rowin && zc_ >= 0 && zc_ < DD) {
            const float* src = simg_ptr + ((size_t)zc_ * HH + sgy) * WW;
            if (fullx) {
                p = *(const float4*)(src + sgxb);
            } else {
                if (sgxb + 0 >= 0 && sgxb + 0 < WW) p.x = src[sgxb + 0];
                if (sgxb + 1 >= 0 && sgxb + 1 < WW) p.y = src[sgxb + 1];
                if (sgxb + 2 >= 0 && sgxb + 2 < WW) p.z = src[sgxb + 2];
                if (sgxb + 3 >= 0 && sgxb + 3 < WW) p.w = src[sgxb + 3];
            }
        }
    };

    // per-thread 5-deep shift ring of 2D box sums (5 fields)
    float ring[5][5];
#pragma unroll
    for (int s = 0; s < 5; ++s)
#pragma unroll
        for (int f = 0; f < 5; ++f) ring[s][f] = 0.f;

    float4 pref;
    prefetch(z0 - 2, pref);     // prologue: slice z0-2 in flight

    for (int zc = z0 - 2; zc <= z1 + 1; ++zc) {
        const int sw = (zc + 10) % 5;          // write slot for slice zc

        // ---- 1. commit prefetched slice zc to LDS; issue loads for zc+1 ----
        if (stager) {
            *(float4*)(slds_base + sw * (RR * RW) + sloff) = pref;
        }
        prefetch(zc + 1, pref);                // in flight across this whole iter

        // mask prefetch for the slice we'll emit this iteration
        const int z = zc - 2;
        const bool emitv = (z >= z0) && (z < z1);
        int um = 0, uf = 0;
        if (emitv) {
            const int vidx = (z * HH + (y0 + ty)) * WW + (x0 + tx);
            um = mmask[vidx];
            uf = fmask[vidx];
        }

        __syncthreads();   // A: raw[sw] visible

        // ---- 2. x-sums (5-wide) of the 5 product fields ----
        for (int i = tid; i < RR * TS; i += 256) {     // 320 tasks
            const int y  = i >> 4;
            const int xo = i & 15;
            float sm = 0.f, sf = 0.f, smm = 0.f, sff = 0.f, smf = 0.f;
#pragma unroll
            for (int dx = 0; dx < 5; ++dx) {
                const float a = rawm[sw][y][xo + 2 + dx];
                const float b = rawf[sw][y][xo + 2 + dx];
                sm += a; sf += b; smm += a * a; sff += b * b; smf += a * b;
            }
            xs[0][y][xo] = sm;
            xs[1][y][xo] = sf;
            xs[2][y][xo] = smm;
            xs[3][y][xo] = sff;
            xs[4][y][xo] = smf;
        }

        __syncthreads();   // B: xs visible

        // ---- 3. y-sums -> register shift ring ----
        float s2d[5];
#pragma unroll
        for (int f = 0; f < 5; ++f) {
            float s = 0.f;
#pragma unroll
            for (int dy = 0; dy < 5; ++dy) s += xs[f][ty + dy][tx];
            s2d[f] = s;
        }
#pragma unroll
        for (int s = 0; s < 4; ++s)
#pragma unroll
            for (int f = 0; f < 5; ++f) ring[s][f] = ring[s + 1][f];
#pragma unroll
        for (int f = 0; f < 5; ++f) ring[4][f] = s2d[f];

        // ---- 4. emit z = zc-2 (box window z-2..z+2 == ring[0..4]) ----
        if (emitv) {
            float sum_m = 0.f, sum_f = 0.f, sum_mm = 0.f, sum_ff = 0.f, sum_mf = 0.f;
#pragma unroll
            for (int s = 0; s < 5; ++s) {
                sum_m  += ring[s][0];
                sum_f  += ring[s][1];
                sum_mm += ring[s][2];
                sum_ff += ring[s][3];
                sum_mf += ring[s][4];
            }
            const int gx = x0 + tx, gy = y0 + ty;
            const int sz  = (zc + 8) % 5;      // slot of slice z   (= zc-2)
            const int szm = (zc + 7) % 5;      // z-1
            const int szp = (zc + 9) % 5;      // z+1
            const int cy = ty + 2, cx = tx + 4;
            const float mc = rawm[sz][cy][cx];
            const float fc = rawf[sz][cy][cx];

            float gxm, gxf, gym, gyf, gzm, gzf;
            if (gx == 0)          { gxm = rawm[sz][cy][cx + 1] - mc;  gxf = rawf[sz][cy][cx + 1] - fc; }
            else if (gx == WW-1)  { gxm = mc - rawm[sz][cy][cx - 1];  gxf = fc - rawf[sz][cy][cx - 1]; }
            else {
                gxm = 0.5f * (rawm[sz][cy][cx + 1] - rawm[sz][cy][cx - 1]);
                gxf = 0.5f * (rawf[sz][cy][cx + 1] - rawf[sz][cy][cx - 1]);
            }
            if (gy == 0)          { gym = rawm[sz][cy + 1][cx] - mc;  gyf = rawf[sz][cy + 1][cx] - fc; }
            else if (gy == HH-1)  { gym = mc - rawm[sz][cy - 1][cx];  gyf = fc - rawf[sz][cy - 1][cx]; }
            else {
                gym = 0.5f * (rawm[sz][cy + 1][cx] - rawm[sz][cy - 1][cx]);
                gyf = 0.5f * (rawf[sz][cy + 1][cx] - rawf[sz][cy - 1][cx]);
            }
            if (z == 0)           { gzm = rawm[szp][cy][cx] - mc;     gzf = rawf[szp][cy][cx] - fc; }
            else if (z == DD-1)   { gzm = mc - rawm[szm][cy][cx];     gzf = fc - rawf[szm][cy][cx]; }
            else {
                gzm = 0.5f * (rawm[szp][cy][cx] - rawm[szm][cy][cx]);
                gzf = 0.5f * (rawf[szp][cy][cx] - rawf[szm][cy][cx]);
            }

            const float u = ((um != 0) || (uf != 0)) ? 1.0f : 0.0f;

            const float npix = 125.0f;
            const float inv_npix = 1.0f / 125.0f;
            const float mean_m = sum_m * inv_npix;
            const float mean_f = sum_f * inv_npix;
            const float var_m = sum_mm - 2.0f * mean_m * sum_m + npix * mean_m * mean_m;
            const float var_f = sum_ff - 2.0f * mean_f * sum_f + npix * mean_f * mean_f;
            const float var_mf = var_m * var_f;
            const float cross = sum_mf - mean_f * sum_m - mean_m * sum_f + npix * mean_m * mean_f;
            const float mmc = mc - mean_m;
            const float fmc = fc - mean_f;
            const bool ok = (var_mf > 1e-5f) && (var_f > 1e-5f) && (fmc != 0.0f) && (mmc != 0.0f);
            float factor = 0.0f;
            if (ok) factor = 2.0f * cross / var_mf * (mmc - cross * fmc / var_f);

            const int vidx = (z * HH + gy) * WW + gx;
            const float nf = -factor * 0.5f * u;
            out[vidx]            = nf * (gzm + gzf);   // channel 0: d/dD
            out[NVOX + vidx]     = nf * (gym + gyf);   // channel 1: d/dH
            out[2 * NVOX + vidx] = nf * (gxm + gxf);   // channel 2: d/dW
        }
        // no trailing barrier: next write slot (zc+1)%5 is disjoint from the
        // read slots {(zc+2),(zc+3),(zc+4)}%5, and xs is only rewritten after
        // the next barrier A.
    }
}

extern "C" void kernel_launch(void* const* d_in, const int* in_sizes, int n_in,
                              void* d_out, int out_size, void* d_ws, size_t ws_size,
                              hipStream_t stream)
{
    const float* mimg  = (const float*)d_in[0];
    const float* fimg  = (const float*)d_in[1];
    const int*   mmask = (const int*)d_in[2];
    const int*   fmask = (const int*)d_in[3];
    float* out = (float*)d_out;

    dim3 grid(WW / TS, HH / TS, DD / ZSEG);   // 12 x 12 x 16 = 2304 blocks
    dim3 block(TS, TS, 1);                    // 256 threads
    hipLaunchKernelGGL(ncc_forces_kernel, grid, block, 0, stream,
                       mimg, fimg, mmask, fmask, out);
}

// Round 3
// 225.231 us; speedup vs baseline: 1.1485x; 1.0212x over previous
//
#include <hip/hip_runtime.h>

// NCC forces, 192^3 fp32 — fused box-sum + gradient + epilogue.
// Round 3: HBM-traffic focus.
//  - XCD-aware swizzle: 1D grid, xcd = b & 7, each XCD owns 2 contiguous
//    z-slabs -> xy-halo re-reads served by that XCD's 4 MB L2.
//  - non-temporal stores for out, non-temporal loads for masks (zero reuse)
//    so L2 keeps image halo lines.
//  - otherwise identical to round 2 (ZSEG 12, 5-deep ring, 2 barriers/slice,
//    float4 pipelined staging).

#define DD 192
#define HH 192
#define WW 192
#define NVOX (DD * HH * WW)
#define TS 16          // output tile 16x16
#define RR 20          // staged rows   = TS + 4
#define RW 24          // staged row width (x0-4 .. x0+20, float4-aligned)
#define ZSEG 12
#define NRING 5
#define NBX (WW / TS)          // 12
#define NBY (HH / TS)          // 12
#define NBZ (DD / ZSEG)        // 16
#define SLABS_PER_XCD (NBZ / 8)  // 2

__global__ __launch_bounds__(256)
void ncc_forces_kernel(const float* __restrict__ mimg,
                       const float* __restrict__ fimg,
                       const int*   __restrict__ mmask,
                       const int*   __restrict__ fmask,
                       float* __restrict__ out)
{
    __shared__ float rawm[NRING][RR][RW];   // 9600 B
    __shared__ float rawf[NRING][RR][RW];   // 9600 B
    __shared__ float xs[5][RR][TS];         // 6400 B   (25.6 KB total)

    // ---- XCD-aware block swizzle ----
    // default HW round-robin: consecutive blockIdx.x -> consecutive XCDs.
    // b&7 = XCD id; give each XCD 2 contiguous z-slabs, all 144 xy tiles each.
    const int b   = blockIdx.x;
    const int xcd = b & 7;
    const int i   = b >> 3;                       // 0..287
    const int sl  = (i >= NBX * NBY) ? 1 : 0;     // which of this XCD's slabs
    const int r   = i - sl * NBX * NBY;           // 0..143
    const int bz  = xcd * SLABS_PER_XCD + sl;
    const int by  = r / NBX;
    const int bx  = r - by * NBX;

    const int tx = threadIdx.x;             // 0..15
    const int ty = threadIdx.y;             // 0..15
    const int tid = ty * TS + tx;
    const int x0 = bx * TS;
    const int y0 = by * TS;
    const int z0 = bz * ZSEG;
    const int z1 = z0 + ZSEG;

    // ---- persistent staging task: 240 tasks = 2 images x 20 rows x 6 quads ----
    const int  simg   = tid / 120;              // 0 = moving, 1 = fixed, 2 = idle
    const bool stager = (simg < 2);
    const int  st     = tid - simg * 120;       // 0..119
    const int  srow   = st / 6;                 // 0..19
    const int  squad  = st - srow * 6;          // 0..5
    const int  sgy    = y0 - 2 + srow;
    const int  sgxb   = x0 - 4 + squad * 4;
    const bool rowin  = (sgy >= 0) && (sgy < HH);
    const bool fullx  = (sgxb >= 0) && (sgxb + 3 < WW);
    const float* simg_ptr = (simg == 1) ? fimg : mimg;
    float* slds_base = (simg == 1) ? &rawf[0][0][0] : &rawm[0][0][0];
    const int  sloff = srow * RW + squad * 4;   // offset within a ring slice

    auto prefetch = [&](int zc_, float4& p) {
        p.x = p.y = p.z = p.w = 0.f;
        if (stager && rowin && zc_ >= 0 && zc_ < DD) {
            const float* src = simg_ptr + ((size_t)zc_ * HH + sgy) * WW;
            if (fullx) {
                p = *(const float4*)(src + sgxb);
            } else {
                if (sgxb + 0 >= 0 && sgxb + 0 < WW) p.x = src[sgxb + 0];
                if (sgxb + 1 >= 0 && sgxb + 1 < WW) p.y = src[sgxb + 1];
                if (sgxb + 2 >= 0 && sgxb + 2 < WW) p.z = src[sgxb + 2];
                if (sgxb + 3 >= 0 && sgxb + 3 < WW) p.w = src[sgxb + 3];
            }
        }
    };

    // per-thread 5-deep shift ring of 2D box sums (5 fields)
    float ring[5][5];
#pragma unroll
    for (int s = 0; s < 5; ++s)
#pragma unroll
        for (int f = 0; f < 5; ++f) ring[s][f] = 0.f;

    float4 pref;
    prefetch(z0 - 2, pref);     // prologue: slice z0-2 in flight

    for (int zc = z0 - 2; zc <= z1 + 1; ++zc) {
        const int sw = (zc + 10) % 5;          // write slot for slice zc

        // ---- 1. commit prefetched slice zc to LDS; issue loads for zc+1 ----
        if (stager) {
            *(float4*)(slds_base + sw * (RR * RW) + sloff) = pref;
        }
        prefetch(zc + 1, pref);                // in flight across this whole iter

        // mask prefetch (non-temporal — zero reuse, keep L2 for image halos)
        const int z = zc - 2;
        const bool emitv = (z >= z0) && (z < z1);
        int um = 0, uf = 0;
        if (emitv) {
            const int vidx = (z * HH + (y0 + ty)) * WW + (x0 + tx);
            um = __builtin_nontemporal_load(&mmask[vidx]);
            uf = __builtin_nontemporal_load(&fmask[vidx]);
        }

        __syncthreads();   // A: raw[sw] visible

        // ---- 2. x-sums (5-wide) of the 5 product fields ----
        for (int i2 = tid; i2 < RR * TS; i2 += 256) {     // 320 tasks
            const int y  = i2 >> 4;
            const int xo = i2 & 15;
            float sm = 0.f, sf = 0.f, smm = 0.f, sff = 0.f, smf = 0.f;
#pragma unroll
            for (int dx = 0; dx < 5; ++dx) {
                const float a = rawm[sw][y][xo + 2 + dx];
                const float b2 = rawf[sw][y][xo + 2 + dx];
                sm += a; sf += b2; smm += a * a; sff += b2 * b2; smf += a * b2;
            }
            xs[0][y][xo] = sm;
            xs[1][y][xo] = sf;
            xs[2][y][xo] = smm;
            xs[3][y][xo] = sff;
            xs[4][y][xo] = smf;
        }

        __syncthreads();   // B: xs visible

        // ---- 3. y-sums -> register shift ring ----
        float s2d[5];
#pragma unroll
        for (int f = 0; f < 5; ++f) {
            float s = 0.f;
#pragma unroll
            for (int dy = 0; dy < 5; ++dy) s += xs[f][ty + dy][tx];
            s2d[f] = s;
        }
#pragma unroll
        for (int s = 0; s < 4; ++s)
#pragma unroll
            for (int f = 0; f < 5; ++f) ring[s][f] = ring[s + 1][f];
#pragma unroll
        for (int f = 0; f < 5; ++f) ring[4][f] = s2d[f];

        // ---- 4. emit z = zc-2 (box window z-2..z+2 == ring[0..4]) ----
        if (emitv) {
            float sum_m = 0.f, sum_f = 0.f, sum_mm = 0.f, sum_ff = 0.f, sum_mf = 0.f;
#pragma unroll
            for (int s = 0; s < 5; ++s) {
                sum_m  += ring[s][0];
                sum_f  += ring[s][1];
                sum_mm += ring[s][2];
                sum_ff += ring[s][3];
                sum_mf += ring[s][4];
            }
            const int gx = x0 + tx, gy = y0 + ty;
            const int sz  = (zc + 8) % 5;      // slot of slice z   (= zc-2)
            const int szm = (zc + 7) % 5;      // z-1
            const int szp = (zc + 9) % 5;      // z+1
            const int cy = ty + 2, cx = tx + 4;
            const float mc = rawm[sz][cy][cx];
            const float fc = rawf[sz][cy][cx];

            float gxm, gxf, gym, gyf, gzm, gzf;
            if (gx == 0)          { gxm = rawm[sz][cy][cx + 1] - mc;  gxf = rawf[sz][cy][cx + 1] - fc; }
            else if (gx == WW-1)  { gxm = mc - rawm[sz][cy][cx - 1];  gxf = fc - rawf[sz][cy][cx - 1]; }
            else {
                gxm = 0.5f * (rawm[sz][cy][cx + 1] - rawm[sz][cy][cx - 1]);
                gxf = 0.5f * (rawf[sz][cy][cx + 1] - rawf[sz][cy][cx - 1]);
            }
            if (gy == 0)          { gym = rawm[sz][cy + 1][cx] - mc;  gyf = rawf[sz][cy + 1][cx] - fc; }
            else if (gy == HH-1)  { gym = mc - rawm[sz][cy - 1][cx];  gyf = fc - rawf[sz][cy - 1][cx]; }
            else {
                gym = 0.5f * (rawm[sz][cy + 1][cx] - rawm[sz][cy - 1][cx]);
                gyf = 0.5f * (rawf[sz][cy + 1][cx] - rawf[sz][cy - 1][cx]);
            }
            if (z == 0)           { gzm = rawm[szp][cy][cx] - mc;     gzf = rawf[szp][cy][cx] - fc; }
            else if (z == DD-1)   { gzm = mc - rawm[szm][cy][cx];     gzf = fc - rawf[szm][cy][cx]; }
            else {
                gzm = 0.5f * (rawm[szp][cy][cx] - rawm[szm][cy][cx]);
                gzf = 0.5f * (rawf[szp][cy][cx] - rawf[szm][cy][cx]);
            }

            const float u = ((um != 0) || (uf != 0)) ? 1.0f : 0.0f;

            const float npix = 125.0f;
            const float inv_npix = 1.0f / 125.0f;
            const float mean_m = sum_m * inv_npix;
            const float mean_f = sum_f * inv_npix;
            const float var_m = sum_mm - 2.0f * mean_m * sum_m + npix * mean_m * mean_m;
            const float var_f = sum_ff - 2.0f * mean_f * sum_f + npix * mean_f * mean_f;
            const float var_mf = var_m * var_f;
            const float cross = sum_mf - mean_f * sum_m - mean_m * sum_f + npix * mean_m * mean_f;
            const float mmc = mc - mean_m;
            const float fmc = fc - mean_f;
            const bool ok = (var_mf > 1e-5f) && (var_f > 1e-5f) && (fmc != 0.0f) && (mmc != 0.0f);
            float factor = 0.0f;
            if (ok) factor = 2.0f * cross / var_mf * (mmc - cross * fmc / var_f);

            const int vidx = (z * HH + gy) * WW + gx;
            const float nf = -factor * 0.5f * u;
            // non-temporal: output is write-once, keep it out of L2
            __builtin_nontemporal_store(nf * (gzm + gzf), &out[vidx]);            // ch 0: d/dD
            __builtin_nontemporal_store(nf * (gym + gyf), &out[NVOX + vidx]);     // ch 1: d/dH
            __builtin_nontemporal_store(nf * (gxm + gxf), &out[2 * NVOX + vidx]); // ch 2: d/dW
        }
        // no trailing barrier: next write slot (zc+1)%5 is disjoint from the
        // read slots {(zc+2),(zc+3),(zc+4)}%5, and xs is only rewritten after
        // the next barrier A.
    }
}

extern "C" void kernel_launch(void* const* d_in, const int* in_sizes, int n_in,
                              void* d_out, int out_size, void* d_ws, size_t ws_size,
                              hipStream_t stream)
{
    const float* mimg  = (const float*)d_in[0];
    const float* fimg  = (const float*)d_in[1];
    const int*   mmask = (const int*)d_in[2];
    const int*   fmask = (const int*)d_in[3];
    float* out = (float*)d_out;

    dim3 grid(NBX * NBY * NBZ, 1, 1);   // 2304 blocks, 1D for swizzle
    dim3 block(TS, TS, 1);              // 256 threads
    hipLaunchKernelGGL(ncc_forces_kernel, grid, block, 0, stream,
                       mimg, fimg, mmask, fmask, out);
}